// Round 6
// baseline (297.305 us; speedup 1.0000x reference)
//
#include <hip/hip_runtime.h>
#include <hip/hip_cooperative_groups.h>
#include <math.h>

namespace cg = cooperative_groups;

#define B_  2
#define L_  2048
#define D_  512
#define DI_ 1024
#define DS_ 16
#define DC_ 4
#define DR_ 32
#define NX_ 64   // DR + 2*DS
#define NC_ 64   // number of scan chunks
#define CT_ 32   // chunk length (NC_*CT_ == L_)
#define KS_ 8    // xproj split-K factor
#define MC_ 32   // dt_proj m-tile

typedef unsigned short u16;
typedef u16   u16x8  __attribute__((ext_vector_type(8)));
typedef __bf16 bf16x8 __attribute__((ext_vector_type(8)));
typedef float  f32x4  __attribute__((ext_vector_type(4)));

__device__ __forceinline__ float sigmoidf_(float v) { return 1.f / (1.f + __expf(-v)); }

__device__ __forceinline__ u16 f2bf(float f) {
    union { float f; unsigned u; } c; c.f = f;
    unsigned u = c.u + 0x7FFFu + ((c.u >> 16) & 1u);
    return (u16)(u >> 16);
}
__device__ __forceinline__ float bf2f(u16 v) {
    union { unsigned u; float f; } c; c.u = ((unsigned)v) << 16; return c.f;
}

// one kernel casting 4 fp32 buffers to bf16 (octet-granular)
__global__ void cast_all(const float* __restrict__ s0, u16* __restrict__ o0, int n0,
                         const float* __restrict__ s1, u16* __restrict__ o1, int n1,
                         const float* __restrict__ s2, u16* __restrict__ o2, int n2,
                         const float* __restrict__ s3, u16* __restrict__ o3, int n3) {
    int i = blockIdx.x * 256 + threadIdx.x;
    const float* s; u16* o; int j = i;
    if (j < n0) { s = s0; o = o0; }
    else { j -= n0;
        if (j < n1) { s = s1; o = o1; }
        else { j -= n1;
            if (j < n2) { s = s2; o = o2; }
            else { j -= n2;
                if (j < n3) { s = s3; o = o3; }
                else return; } } }
    const float4* p = reinterpret_cast<const float4*>(s) + (size_t)j * 2;
    float4 v0 = p[0], v1 = p[1];
    u16x8 r;
    r[0] = f2bf(v0.x); r[1] = f2bf(v0.y); r[2] = f2bf(v0.z); r[3] = f2bf(v0.w);
    r[4] = f2bf(v1.x); r[5] = f2bf(v1.y); r[6] = f2bf(v1.z); r[7] = f2bf(v1.w);
    reinterpret_cast<u16x8*>(o)[j] = r;
}

// NT bf16 MFMA GEMM: C[m,n] = dot(A[m,:K], B[n,:K]). 128x128 tile, BK=64.
// Writes bf16. Columns [0,N0) -> out0 (stride N0), rest -> out1 (stride N1).
template<int K, int N0, int N1>
__global__ __launch_bounds__(256, 2) void gemm_mfma_nt(
    const u16* __restrict__ Ab, const u16* __restrict__ Bb,
    u16* __restrict__ out0, u16* __restrict__ out1) {
    __shared__ u16 As[128 * 64];
    __shared__ u16 Bs[128 * 64];
    const int bm = blockIdx.y * 128, bn = blockIdx.x * 128;
    const int t = threadIdx.x;
    const int w = t >> 6, l = t & 63;
    const int wm = (w >> 1) * 64, wn = (w & 1) * 64;
    const int lr = l & 15;
    const int lk = (l >> 4) * 8;

    f32x4 acc[4][4] = {};

    for (int k0 = 0; k0 < K; k0 += 64) {
        #pragma unroll
        for (int i = 0; i < 4; i++) {
            int q  = i * 256 + t;
            int r  = q >> 3;
            int c0 = ((q ^ r) & 7) << 3;
            __builtin_amdgcn_global_load_lds(
                (const __attribute__((address_space(1))) void*)(Ab + (size_t)(bm + r) * K + k0 + c0),
                (__attribute__((address_space(3))) void*)(As + (i * 256 + w * 64) * 8),
                16, 0, 0);
            __builtin_amdgcn_global_load_lds(
                (const __attribute__((address_space(1))) void*)(Bb + (size_t)(bn + r) * K + k0 + c0),
                (__attribute__((address_space(3))) void*)(Bs + (i * 256 + w * 64) * 8),
                16, 0, 0);
        }
        __syncthreads();
        #pragma unroll
        for (int kk = 0; kk < 2; kk++) {
            bf16x8 a[4], b[4];
            #pragma unroll
            for (int m = 0; m < 4; m++) {
                int row  = wm + m * 16 + lr;
                int byte = (row * 128 + (kk * 32 + lk) * 2) ^ ((row & 7) << 4);
                a[m] = *reinterpret_cast<const bf16x8*>(reinterpret_cast<const char*>(As) + byte);
            }
            #pragma unroll
            for (int n = 0; n < 4; n++) {
                int row  = wn + n * 16 + lr;
                int byte = (row * 128 + (kk * 32 + lk) * 2) ^ ((row & 7) << 4);
                b[n] = *reinterpret_cast<const bf16x8*>(reinterpret_cast<const char*>(Bs) + byte);
            }
            #pragma unroll
            for (int m = 0; m < 4; m++)
                #pragma unroll
                for (int n = 0; n < 4; n++)
                    acc[m][n] = __builtin_amdgcn_mfma_f32_16x16x32_bf16(a[m], b[n], acc[m][n], 0, 0, 0);
        }
        __syncthreads();
    }

    u16* obase = (bn < N0) ? out0 : out1;
    const int stride = (bn < N0) ? N0 : N1;
    const int bcol   = (bn < N0) ? bn : bn - N0;
    #pragma unroll
    for (int m = 0; m < 4; m++) {
        #pragma unroll
        for (int j = 0; j < 4; j++) {
            int row = bm + wm + m * 16 + (l >> 4) * 4 + j;
            #pragma unroll
            for (int n = 0; n < 4; n++)
                obase[(size_t)row * stride + bcol + wn + n * 16 + lr] = f2bf(acc[m][n][j]);
        }
    }
}

// xproj as split-K MFMA: A=[4096][1024] bf16, B=[64][1024] bf16,
// tile 128(M)x64(N), BK=64. part[ks][4096][64] fp32.
__global__ __launch_bounds__(256, 2) void xproj_mfma(
    const u16* __restrict__ Ab, const u16* __restrict__ Bb, float* __restrict__ part) {
    __shared__ u16 As[128 * 64];
    __shared__ u16 Bs[64 * 64];
    const int ks = blockIdx.x;
    const int bm = blockIdx.y * 128;
    const int t = threadIdx.x;
    const int w = t >> 6, l = t & 63;
    const int wm = (w >> 1) * 64, wn = (w & 1) * 32;
    const int lr = l & 15;
    const int lk = (l >> 4) * 8;

    f32x4 acc[4][2] = {};

    for (int it = 0; it < (1024 / KS_) / 64; it++) {
        int k0 = ks * (1024 / KS_) + it * 64;
        #pragma unroll
        for (int i = 0; i < 4; i++) {
            int q  = i * 256 + t;
            int r  = q >> 3;
            int c0 = ((q ^ r) & 7) << 3;
            __builtin_amdgcn_global_load_lds(
                (const __attribute__((address_space(1))) void*)(Ab + (size_t)(bm + r) * 1024 + k0 + c0),
                (__attribute__((address_space(3))) void*)(As + (i * 256 + w * 64) * 8),
                16, 0, 0);
        }
        #pragma unroll
        for (int i = 0; i < 2; i++) {
            int q  = i * 256 + t;
            int r  = q >> 3;
            int c0 = ((q ^ r) & 7) << 3;
            __builtin_amdgcn_global_load_lds(
                (const __attribute__((address_space(1))) void*)(Bb + (size_t)r * 1024 + k0 + c0),
                (__attribute__((address_space(3))) void*)(Bs + (i * 256 + w * 64) * 8),
                16, 0, 0);
        }
        __syncthreads();
        #pragma unroll
        for (int kk = 0; kk < 2; kk++) {
            bf16x8 a[4], b[2];
            #pragma unroll
            for (int m = 0; m < 4; m++) {
                int row  = wm + m * 16 + lr;
                int byte = (row * 128 + (kk * 32 + lk) * 2) ^ ((row & 7) << 4);
                a[m] = *reinterpret_cast<const bf16x8*>(reinterpret_cast<const char*>(As) + byte);
            }
            #pragma unroll
            for (int n = 0; n < 2; n++) {
                int row  = wn + n * 16 + lr;
                int byte = (row * 128 + (kk * 32 + lk) * 2) ^ ((row & 7) << 4);
                b[n] = *reinterpret_cast<const bf16x8*>(reinterpret_cast<const char*>(Bs) + byte);
            }
            #pragma unroll
            for (int m = 0; m < 4; m++)
                #pragma unroll
                for (int n = 0; n < 2; n++)
                    acc[m][n] = __builtin_amdgcn_mfma_f32_16x16x32_bf16(a[m], b[n], acc[m][n], 0, 0, 0);
        }
        __syncthreads();
    }

    float* obase = part + (size_t)ks * (4096 * 64);
    #pragma unroll
    for (int m = 0; m < 4; m++) {
        #pragma unroll
        for (int j = 0; j < 4; j++) {
            int row = bm + wm + m * 16 + (l >> 4) * 4 + j;
            #pragma unroll
            for (int n = 0; n < 2; n++)
                obase[(size_t)row * 64 + wn + n * 16 + lr] = acc[m][n][j];
        }
    }
}

// out_proj: A=[4096][1024] bf16, B=[512][1024] bf16 -> omb [4096][512] bf16.
// tile 128(M)x64(N), grid (8,32)=256 blocks (1/CU).
__global__ __launch_bounds__(256, 2) void oproj_mfma(
    const u16* __restrict__ Ab, const u16* __restrict__ Bb, u16* __restrict__ outb) {
    __shared__ u16 As[128 * 64];
    __shared__ u16 Bs[64 * 64];
    const int bn = blockIdx.x * 64;
    const int bm = blockIdx.y * 128;
    const int t = threadIdx.x;
    const int w = t >> 6, l = t & 63;
    const int wm = (w >> 1) * 64, wn = (w & 1) * 32;
    const int lr = l & 15;
    const int lk = (l >> 4) * 8;

    f32x4 acc[4][2] = {};

    for (int k0 = 0; k0 < 1024; k0 += 64) {
        #pragma unroll
        for (int i = 0; i < 4; i++) {
            int q  = i * 256 + t;
            int r  = q >> 3;
            int c0 = ((q ^ r) & 7) << 3;
            __builtin_amdgcn_global_load_lds(
                (const __attribute__((address_space(1))) void*)(Ab + (size_t)(bm + r) * 1024 + k0 + c0),
                (__attribute__((address_space(3))) void*)(As + (i * 256 + w * 64) * 8),
                16, 0, 0);
        }
        #pragma unroll
        for (int i = 0; i < 2; i++) {
            int q  = i * 256 + t;
            int r  = q >> 3;
            int c0 = ((q ^ r) & 7) << 3;
            __builtin_amdgcn_global_load_lds(
                (const __attribute__((address_space(1))) void*)(Bb + (size_t)(bn + r) * 1024 + k0 + c0),
                (__attribute__((address_space(3))) void*)(Bs + (i * 256 + w * 64) * 8),
                16, 0, 0);
        }
        __syncthreads();
        #pragma unroll
        for (int kk = 0; kk < 2; kk++) {
            bf16x8 a[4], b[2];
            #pragma unroll
            for (int m = 0; m < 4; m++) {
                int row  = wm + m * 16 + lr;
                int byte = (row * 128 + (kk * 32 + lk) * 2) ^ ((row & 7) << 4);
                a[m] = *reinterpret_cast<const bf16x8*>(reinterpret_cast<const char*>(As) + byte);
            }
            #pragma unroll
            for (int n = 0; n < 2; n++) {
                int row  = wn + n * 16 + lr;
                int byte = (row * 128 + (kk * 32 + lk) * 2) ^ ((row & 7) << 4);
                b[n] = *reinterpret_cast<const bf16x8*>(reinterpret_cast<const char*>(Bs) + byte);
            }
            #pragma unroll
            for (int m = 0; m < 4; m++)
                #pragma unroll
                for (int n = 0; n < 2; n++)
                    acc[m][n] = __builtin_amdgcn_mfma_f32_16x16x32_bf16(a[m], b[n], acc[m][n], 0, 0, 0);
        }
        __syncthreads();
    }

    #pragma unroll
    for (int m = 0; m < 4; m++) {
        #pragma unroll
        for (int j = 0; j < 4; j++) {
            int row = bm + wm + m * 16 + (l >> 4) * 4 + j;
            #pragma unroll
            for (int n = 0; n < 2; n++)
                outb[(size_t)row * D_ + bn + wn + n * 16 + lr] = f2bf(acc[m][n][j]);
        }
    }
}

// depthwise causal conv + SiLU; bf16 in (xi), bf16 out (u). 8 d's per thread.
__global__ void conv_silu(const u16* __restrict__ xib, const float* __restrict__ cw,
                          const float* __restrict__ cb, u16* __restrict__ ub) {
    int i = blockIdx.x * 256 + threadIdx.x;           // octet index over B*L*DI/8
    int e0 = i * 8;
    int d0 = e0 & (DI_ - 1);
    int bl = e0 >> 10;
    int l  = bl & (L_ - 1);
    float acc[8];
    #pragma unroll
    for (int j = 0; j < 8; j++) acc[j] = cb[d0 + j];
    #pragma unroll
    for (int k = 0; k < DC_; k++) {
        int lk = l - (DC_ - 1) + k;
        if (lk >= 0) {
            u16x8 x8 = *reinterpret_cast<const u16x8*>(xib + (size_t)(bl - (DC_ - 1) + k) * DI_ + d0);
            #pragma unroll
            for (int j = 0; j < 8; j++)
                acc[j] = fmaf(bf2f(x8[j]), cw[(d0 + j) * DC_ + k], acc[j]);
        }
    }
    u16x8 r;
    #pragma unroll
    for (int j = 0; j < 8; j++) {
        float v = acc[j] * sigmoidf_(acc[j]);
        r[j] = f2bf(v);
    }
    reinterpret_cast<u16x8*>(ub)[i] = r;
}

// Fused: reduce xproj partials (dt cols into LDS; bx==0 also writes full xdbl)
// then delta = softplus(dts @ W_dt^T + b_dt) -> bf16.
__global__ __launch_bounds__(256) void reduce_dt(
    const float* __restrict__ part, const float* __restrict__ Wdt,
    const float* __restrict__ bdt, float* __restrict__ xdbl,
    u16* __restrict__ deltab) {
    __shared__ float Wl[256 * 33];
    __shared__ float dts[MC_][DR_];
    const int t  = threadIdx.x;
    const int d0 = blockIdx.x * 256;
    const int m0 = blockIdx.y * MC_;

    // Phase A: reduce dt columns for this m-tile
    for (int i = t; i < MC_ * DR_; i += 256) {
        int m = i >> 5, r = i & 31;
        float s = 0.f;
        #pragma unroll
        for (int ks = 0; ks < KS_; ks++) s += part[(size_t)ks * (4096 * 64) + (m0 + m) * 64 + r];
        dts[m][r] = s;
    }
    // bx==0 blocks also emit the full reduced xdbl rows (all 64 cols)
    if (blockIdx.x == 0) {
        for (int i = t; i < MC_ * 64; i += 256) {
            int m = i >> 6, n = i & 63;
            float s = 0.f;
            #pragma unroll
            for (int ks = 0; ks < KS_; ks++) s += part[(size_t)ks * (4096 * 64) + (m0 + m) * 64 + n];
            xdbl[(size_t)(m0 + m) * 64 + n] = s;
        }
    }
    // stage W_dt rows [d0, d0+256) coalesced -> padded LDS
    {
        const float4* src = reinterpret_cast<const float4*>(Wdt + (size_t)d0 * DR_);
        #pragma unroll
        for (int i = 0; i < 8; i++) {
            int e = (i * 256 + t);
            int r4 = e & 7, row = e >> 3;
            float4 v = src[e];
            float* dst = &Wl[row * 33 + r4 * 4];
            dst[0] = v.x; dst[1] = v.y; dst[2] = v.z; dst[3] = v.w;
        }
    }
    __syncthreads();

    float wreg[DR_];
    #pragma unroll
    for (int r = 0; r < DR_; r++) wreg[r] = Wl[t * 33 + r];
    const float bias = bdt[d0 + t];

    for (int m = 0; m < MC_; m++) {
        float a0 = bias, a1 = 0.f, a2 = 0.f, a3 = 0.f;
        #pragma unroll
        for (int r = 0; r < DR_; r += 4) {
            a0 = fmaf(dts[m][r],     wreg[r],     a0);
            a1 = fmaf(dts[m][r + 1], wreg[r + 1], a1);
            a2 = fmaf(dts[m][r + 2], wreg[r + 2], a2);
            a3 = fmaf(dts[m][r + 3], wreg[r + 3], a3);
        }
        float acc = (a0 + a1) + (a2 + a3);
        float sp  = fmaxf(acc, 0.f) + __logf(1.f + __expf(-fabsf(acc)));
        deltab[(size_t)(m0 + m) * DI_ + d0 + t] = f2bf(sp);
    }
}

// Fused chunked selective scan: phase1 (per-chunk h|0, prodA) -> grid.sync ->
// phase2 (sequential chunk-carry) -> grid.sync -> phase3 (replay + y + gate).
__global__ __launch_bounds__(256, 2) void scan_fused(
    const u16* __restrict__ deltab, const u16* __restrict__ ub,
    const float* __restrict__ xdbl, const float* __restrict__ A_log,
    const u16* __restrict__ zb, const float* __restrict__ Dp,
    float* __restrict__ hz, float* __restrict__ pA, float* __restrict__ hin,
    u16* __restrict__ yvb) {
    const int d = blockIdx.x * 256 + threadIdx.x;
    const int c = blockIdx.y;
    const int b = blockIdx.z;
    __shared__ float Brow[CT_][DS_];
    __shared__ float Crow[CT_][DS_];
    for (int i = threadIdx.x; i < CT_ * DS_; i += 256) {
        int t = i >> 4, s = i & 15;
        size_t rb = (size_t)(b * L_ + c * CT_ + t) * NX_;
        Brow[t][s] = xdbl[rb + DR_ + s];
        Crow[t][s] = xdbl[rb + DR_ + DS_ + s];
    }
    __syncthreads();

    float a[DS_], h[DS_], p[DS_];
    #pragma unroll
    for (int s = 0; s < DS_; s++) {
        a[s] = -__expf(A_log[d * DS_ + s]);
        h[s] = 0.f; p[s] = 1.f;
    }
    size_t base = (size_t)(b * L_ + c * CT_) * DI_ + d;
    for (int t = 0; t < CT_; t++) {
        float dl = bf2f(deltab[base + (size_t)t * DI_]);
        float uv = bf2f(ub[base + (size_t)t * DI_]);
        float dlu = dl * uv;
        #pragma unroll
        for (int s = 0; s < DS_; s++) {
            float dA = __expf(dl * a[s]);
            p[s] *= dA;
            h[s] = fmaf(dA, h[s], dlu * Brow[t][s]);
        }
    }
    size_t o1 = ((size_t)(b * NC_ + c) * DI_ + d) * DS_;
    #pragma unroll
    for (int s = 0; s < DS_; s++) { hz[o1 + s] = h[s]; pA[o1 + s] = p[s]; }

    cg::this_grid().sync();

    // phase 2: chunk carry (first 32768 flat threads)
    {
        int linb = blockIdx.x + 4 * (blockIdx.y + 64 * blockIdx.z);
        int fid = linb * 256 + threadIdx.x;
        if (fid < B_ * DI_ * DS_) {
            int bb = fid >> 14;
            int ds = fid & (DI_ * DS_ - 1);
            float hh = 0.f;
            for (int c2 = 0; c2 < NC_; c2++) {
                size_t o = (size_t)(bb * NC_ + c2) * DI_ * DS_ + ds;
                hin[o] = hh;
                hh = fmaf(pA[o], hh, hz[o]);
            }
        }
    }

    cg::this_grid().sync();

    // phase 3: replay with carried h_in, emit gated y
    #pragma unroll
    for (int s = 0; s < DS_; s++) h[s] = hin[o1 + s];
    float Dpd = Dp[d];
    for (int t = 0; t < CT_; t++) {
        float dl = bf2f(deltab[base + (size_t)t * DI_]);
        float uv = bf2f(ub[base + (size_t)t * DI_]);
        float dlu = dl * uv;
        float acc = 0.f;
        #pragma unroll
        for (int s = 0; s < DS_; s++) {
            float dA = __expf(dl * a[s]);
            h[s] = fmaf(dA, h[s], dlu * Brow[t][s]);
            acc = fmaf(h[s], Crow[t][s], acc);
        }
        float zv = bf2f(zb[base + (size_t)t * DI_]);
        float yval = fmaf(uv, Dpd, acc);
        yvb[base + (size_t)t * DI_] = f2bf(yval * (zv * sigmoidf_(zv)));
    }
}

__global__ void ln_res(const u16* __restrict__ omb, const float* __restrict__ x,
                       const float* __restrict__ lw, const float* __restrict__ lb,
                       float* __restrict__ out) {
    const int row = blockIdx.x;                    // b*L
    const u16* r = omb + (size_t)row * D_;
    float v0 = bf2f(r[threadIdx.x]), v1 = bf2f(r[threadIdx.x + 256]);
    float s = v0 + v1, sq = v0 * v0 + v1 * v1;
    #pragma unroll
    for (int off = 32; off; off >>= 1) {
        s  += __shfl_down(s, off);
        sq += __shfl_down(sq, off);
    }
    __shared__ float ss[4], ssq[4];
    int w = threadIdx.x >> 6;
    if ((threadIdx.x & 63) == 0) { ss[w] = s; ssq[w] = sq; }
    __syncthreads();
    float ts  = ss[0] + ss[1] + ss[2] + ss[3];
    float tsq = ssq[0] + ssq[1] + ssq[2] + ssq[3];
    float mu  = ts * (1.f / 512.f);
    float var = tsq * (1.f / 512.f) - mu * mu;
    float inv = rsqrtf(var + 1e-6f);
    size_t i0 = (size_t)row * D_ + threadIdx.x;
    out[i0]       = x[i0]       + (v0 - mu) * inv * lw[threadIdx.x]       + lb[threadIdx.x];
    out[i0 + 256] = x[i0 + 256] + (v1 - mu) * inv * lw[threadIdx.x + 256] + lb[threadIdx.x + 256];
}

extern "C" void kernel_launch(void* const* d_in, const int* in_sizes, int n_in,
                              void* d_out, int out_size, void* d_ws, size_t ws_size,
                              hipStream_t stream) {
    const float* x      = (const float*)d_in[0];
    const float* W_in   = (const float*)d_in[1];
    const float* conv_w = (const float*)d_in[2];
    const float* conv_b = (const float*)d_in[3];
    const float* W_xp   = (const float*)d_in[4];
    const float* W_dt   = (const float*)d_in[5];
    const float* b_dt   = (const float*)d_in[6];
    const float* A_log  = (const float*)d_in[7];
    const float* Dp     = (const float*)d_in[8];
    const float* W_out  = (const float*)d_in[9];
    const float* ln_w   = (const float*)d_in[10];
    const float* ln_b   = (const float*)d_in[11];
    float* out = (float*)d_out;

    const size_t NBL = (size_t)B_ * L_ * DI_;          // 4,194,304
    u16* xib  = (u16*)d_ws;                            // B*L*DI bf16
    u16* zb   = xib + NBL;
    u16* ub   = zb  + NBL;
    u16* yvb  = ub  + NBL;
    u16* omb  = yvb + NBL;                             // B*L*D bf16
    u16* xb   = omb + (size_t)B_ * L_ * D_;            // B*L*D bf16
    u16* wb   = xb  + (size_t)B_ * L_ * D_;            // 2*DI*D bf16
    u16* wxb  = wb  + (size_t)2 * DI_ * D_;            // 64*1024 bf16
    u16* wob  = wxb + (size_t)NX_ * DI_;               // D*DI bf16
    u16* deltab = wob + (size_t)D_ * DI_;              // NBL bf16
    float* xdbl  = (float*)(deltab + NBL);             // B*L*NX f32
    float* part  = xdbl + (size_t)B_ * L_ * NX_;       // KS*4096*64 f32
    float* hz    = part + (size_t)KS_ * 4096 * 64;
    float* pAb   = hz + (size_t)B_ * NC_ * DI_ * DS_;
    float* hin   = pAb + (size_t)B_ * NC_ * DI_ * DS_;

    const int n0 = B_ * L_ * D_ / 8, n1 = 2 * DI_ * D_ / 8;
    const int n2 = NX_ * DI_ / 8,    n3 = D_ * DI_ / 8;
    // 0. all fp32 -> bf16 casts in one kernel
    cast_all<<<(n0 + n1 + n2 + n3 + 255) / 256, 256, 0, stream>>>(
        x, xb, n0, W_in, wb, n1, W_xp, wxb, n2, W_out, wob, n3);
    // 1. in_proj (bf16 MFMA): [4096,512] x [2048,512]^T -> xib | zb (bf16)
    gemm_mfma_nt<512, 1024, 1024>
        <<<dim3(2048 / 128, 4096 / 128), 256, 0, stream>>>(xb, wb, xib, zb);
    // 2. depthwise causal conv + SiLU -> ub (bf16)
    conv_silu<<<(int)(NBL / 8 / 256), 256, 0, stream>>>(xib, conv_w, conv_b, ub);
    // 3. x_proj as split-K MFMA
    xproj_mfma<<<dim3(KS_, 4096 / 128), 256, 0, stream>>>(ub, wxb, part);
    // 4. fused reduce + dt_proj + softplus -> xdbl (f32) + deltab (bf16)
    reduce_dt<<<dim3(DI_ / 256, (B_ * L_) / MC_), 256, 0, stream>>>(part, W_dt, b_dt, xdbl, deltab);
    // 5. fused cooperative scan (p1 + carry + p2)
    {
        const u16* da = deltab; const u16* ua = ub; const float* xa = xdbl;
        const float* Aa = A_log; const u16* za = zb; const float* Da = Dp;
        float* hza = hz; float* pa = pAb; float* ha = hin; u16* ya = yvb;
        void* ka[] = { (void*)&da, (void*)&ua, (void*)&xa, (void*)&Aa, (void*)&za,
                       (void*)&Da, (void*)&hza, (void*)&pa, (void*)&ha, (void*)&ya };
        hipLaunchCooperativeKernel((const void*)scan_fused,
                                   dim3(DI_ / 256, NC_, B_), dim3(256),
                                   ka, 0, stream);
    }
    // 6. out_proj (bf16 MFMA, 128x64 tile, 256 blocks): -> omb (bf16)
    oproj_mfma<<<dim3(D_ / 64, 4096 / 128), 256, 0, stream>>>(yvb, wob, omb);
    // 7. LayerNorm + residual
    ln_res<<<B_ * L_, 256, 0, stream>>>(omb, x, ln_w, ln_b, out);
}

// Round 7
// 159.593 us; speedup vs baseline: 1.8629x; 1.8629x over previous
//
#include <hip/hip_runtime.h>
#include <math.h>

#define B_  2
#define L_  2048
#define D_  512
#define DI_ 1024
#define DS_ 16
#define DC_ 4
#define DR_ 32
#define NX_ 64   // DR + 2*DS
#define NC_ 64   // number of scan chunks
#define CT_ 32   // chunk length (NC_*CT_ == L_)
#define KS_ 8    // xproj split-K factor
#define MC_ 32   // dt_proj m-tile

typedef unsigned short u16;
typedef u16   u16x8  __attribute__((ext_vector_type(8)));
typedef __bf16 bf16x8 __attribute__((ext_vector_type(8)));
typedef float  f32x4  __attribute__((ext_vector_type(4)));

__device__ __forceinline__ float sigmoidf_(float v) { return 1.f / (1.f + __expf(-v)); }

__device__ __forceinline__ u16 f2bf(float f) {
    union { float f; unsigned u; } c; c.f = f;
    unsigned u = c.u + 0x7FFFu + ((c.u >> 16) & 1u);
    return (u16)(u >> 16);
}
__device__ __forceinline__ float bf2f(u16 v) {
    union { unsigned u; float f; } c; c.u = ((unsigned)v) << 16; return c.f;
}

// one kernel casting 4 fp32 buffers to bf16 (octet-granular)
__global__ void cast_all(const float* __restrict__ s0, u16* __restrict__ o0, int n0,
                         const float* __restrict__ s1, u16* __restrict__ o1, int n1,
                         const float* __restrict__ s2, u16* __restrict__ o2, int n2,
                         const float* __restrict__ s3, u16* __restrict__ o3, int n3) {
    int i = blockIdx.x * 256 + threadIdx.x;
    const float* s; u16* o; int j = i;
    if (j < n0) { s = s0; o = o0; }
    else { j -= n0;
        if (j < n1) { s = s1; o = o1; }
        else { j -= n1;
            if (j < n2) { s = s2; o = o2; }
            else { j -= n2;
                if (j < n3) { s = s3; o = o3; }
                else return; } } }
    const float4* p = reinterpret_cast<const float4*>(s) + (size_t)j * 2;
    float4 v0 = p[0], v1 = p[1];
    u16x8 r;
    r[0] = f2bf(v0.x); r[1] = f2bf(v0.y); r[2] = f2bf(v0.z); r[3] = f2bf(v0.w);
    r[4] = f2bf(v1.x); r[5] = f2bf(v1.y); r[6] = f2bf(v1.z); r[7] = f2bf(v1.w);
    reinterpret_cast<u16x8*>(o)[j] = r;
}

// NT bf16 MFMA GEMM: C[m,n] = dot(A[m,:K], B[n,:K]). 128x128 tile, BK=64.
// Writes bf16. Columns [0,N0) -> out0 (stride N0), rest -> out1 (stride N1).
template<int K, int N0, int N1>
__global__ __launch_bounds__(256, 2) void gemm_mfma_nt(
    const u16* __restrict__ Ab, const u16* __restrict__ Bb,
    u16* __restrict__ out0, u16* __restrict__ out1) {
    __shared__ u16 As[128 * 64];
    __shared__ u16 Bs[128 * 64];
    const int bm = blockIdx.y * 128, bn = blockIdx.x * 128;
    const int t = threadIdx.x;
    const int w = t >> 6, l = t & 63;
    const int wm = (w >> 1) * 64, wn = (w & 1) * 64;
    const int lr = l & 15;
    const int lk = (l >> 4) * 8;

    f32x4 acc[4][4] = {};

    for (int k0 = 0; k0 < K; k0 += 64) {
        #pragma unroll
        for (int i = 0; i < 4; i++) {
            int q  = i * 256 + t;
            int r  = q >> 3;
            int c0 = ((q ^ r) & 7) << 3;
            __builtin_amdgcn_global_load_lds(
                (const __attribute__((address_space(1))) void*)(Ab + (size_t)(bm + r) * K + k0 + c0),
                (__attribute__((address_space(3))) void*)(As + (i * 256 + w * 64) * 8),
                16, 0, 0);
            __builtin_amdgcn_global_load_lds(
                (const __attribute__((address_space(1))) void*)(Bb + (size_t)(bn + r) * K + k0 + c0),
                (__attribute__((address_space(3))) void*)(Bs + (i * 256 + w * 64) * 8),
                16, 0, 0);
        }
        __syncthreads();
        #pragma unroll
        for (int kk = 0; kk < 2; kk++) {
            bf16x8 a[4], b[4];
            #pragma unroll
            for (int m = 0; m < 4; m++) {
                int row  = wm + m * 16 + lr;
                int byte = (row * 128 + (kk * 32 + lk) * 2) ^ ((row & 7) << 4);
                a[m] = *reinterpret_cast<const bf16x8*>(reinterpret_cast<const char*>(As) + byte);
            }
            #pragma unroll
            for (int n = 0; n < 4; n++) {
                int row  = wn + n * 16 + lr;
                int byte = (row * 128 + (kk * 32 + lk) * 2) ^ ((row & 7) << 4);
                b[n] = *reinterpret_cast<const bf16x8*>(reinterpret_cast<const char*>(Bs) + byte);
            }
            #pragma unroll
            for (int m = 0; m < 4; m++)
                #pragma unroll
                for (int n = 0; n < 4; n++)
                    acc[m][n] = __builtin_amdgcn_mfma_f32_16x16x32_bf16(a[m], b[n], acc[m][n], 0, 0, 0);
        }
        __syncthreads();
    }

    u16* obase = (bn < N0) ? out0 : out1;
    const int stride = (bn < N0) ? N0 : N1;
    const int bcol   = (bn < N0) ? bn : bn - N0;
    #pragma unroll
    for (int m = 0; m < 4; m++) {
        #pragma unroll
        for (int j = 0; j < 4; j++) {
            int row = bm + wm + m * 16 + (l >> 4) * 4 + j;
            #pragma unroll
            for (int n = 0; n < 4; n++)
                obase[(size_t)row * stride + bcol + wn + n * 16 + lr] = f2bf(acc[m][n][j]);
        }
    }
}

// xproj as split-K MFMA: A=[4096][1024] bf16, B=[64][1024] bf16,
// tile 128(M)x64(N), BK=64. part[ks][4096][64] fp32.
__global__ __launch_bounds__(256, 2) void xproj_mfma(
    const u16* __restrict__ Ab, const u16* __restrict__ Bb, float* __restrict__ part) {
    __shared__ u16 As[128 * 64];
    __shared__ u16 Bs[64 * 64];
    const int ks = blockIdx.x;
    const int bm = blockIdx.y * 128;
    const int t = threadIdx.x;
    const int w = t >> 6, l = t & 63;
    const int wm = (w >> 1) * 64, wn = (w & 1) * 32;
    const int lr = l & 15;
    const int lk = (l >> 4) * 8;

    f32x4 acc[4][2] = {};

    for (int it = 0; it < (1024 / KS_) / 64; it++) {
        int k0 = ks * (1024 / KS_) + it * 64;
        #pragma unroll
        for (int i = 0; i < 4; i++) {
            int q  = i * 256 + t;
            int r  = q >> 3;
            int c0 = ((q ^ r) & 7) << 3;
            __builtin_amdgcn_global_load_lds(
                (const __attribute__((address_space(1))) void*)(Ab + (size_t)(bm + r) * 1024 + k0 + c0),
                (__attribute__((address_space(3))) void*)(As + (i * 256 + w * 64) * 8),
                16, 0, 0);
        }
        #pragma unroll
        for (int i = 0; i < 2; i++) {
            int q  = i * 256 + t;
            int r  = q >> 3;
            int c0 = ((q ^ r) & 7) << 3;
            __builtin_amdgcn_global_load_lds(
                (const __attribute__((address_space(1))) void*)(Bb + (size_t)r * 1024 + k0 + c0),
                (__attribute__((address_space(3))) void*)(Bs + (i * 256 + w * 64) * 8),
                16, 0, 0);
        }
        __syncthreads();
        #pragma unroll
        for (int kk = 0; kk < 2; kk++) {
            bf16x8 a[4], b[2];
            #pragma unroll
            for (int m = 0; m < 4; m++) {
                int row  = wm + m * 16 + lr;
                int byte = (row * 128 + (kk * 32 + lk) * 2) ^ ((row & 7) << 4);
                a[m] = *reinterpret_cast<const bf16x8*>(reinterpret_cast<const char*>(As) + byte);
            }
            #pragma unroll
            for (int n = 0; n < 2; n++) {
                int row  = wn + n * 16 + lr;
                int byte = (row * 128 + (kk * 32 + lk) * 2) ^ ((row & 7) << 4);
                b[n] = *reinterpret_cast<const bf16x8*>(reinterpret_cast<const char*>(Bs) + byte);
            }
            #pragma unroll
            for (int m = 0; m < 4; m++)
                #pragma unroll
                for (int n = 0; n < 2; n++)
                    acc[m][n] = __builtin_amdgcn_mfma_f32_16x16x32_bf16(a[m], b[n], acc[m][n], 0, 0, 0);
        }
        __syncthreads();
    }

    float* obase = part + (size_t)ks * (4096 * 64);
    #pragma unroll
    for (int m = 0; m < 4; m++) {
        #pragma unroll
        for (int j = 0; j < 4; j++) {
            int row = bm + wm + m * 16 + (l >> 4) * 4 + j;
            #pragma unroll
            for (int n = 0; n < 2; n++)
                obase[(size_t)row * 64 + wn + n * 16 + lr] = acc[m][n][j];
        }
    }
}

// out_proj: A=[4096][1024] bf16, B=[512][1024] bf16 -> omb [4096][512] bf16.
// tile 128(M)x64(N), grid (8,32)=256 blocks (1/CU).
__global__ __launch_bounds__(256, 2) void oproj_mfma(
    const u16* __restrict__ Ab, const u16* __restrict__ Bb, u16* __restrict__ outb) {
    __shared__ u16 As[128 * 64];
    __shared__ u16 Bs[64 * 64];
    const int bn = blockIdx.x * 64;
    const int bm = blockIdx.y * 128;
    const int t = threadIdx.x;
    const int w = t >> 6, l = t & 63;
    const int wm = (w >> 1) * 64, wn = (w & 1) * 32;
    const int lr = l & 15;
    const int lk = (l >> 4) * 8;

    f32x4 acc[4][2] = {};

    for (int k0 = 0; k0 < 1024; k0 += 64) {
        #pragma unroll
        for (int i = 0; i < 4; i++) {
            int q  = i * 256 + t;
            int r  = q >> 3;
            int c0 = ((q ^ r) & 7) << 3;
            __builtin_amdgcn_global_load_lds(
                (const __attribute__((address_space(1))) void*)(Ab + (size_t)(bm + r) * 1024 + k0 + c0),
                (__attribute__((address_space(3))) void*)(As + (i * 256 + w * 64) * 8),
                16, 0, 0);
        }
        #pragma unroll
        for (int i = 0; i < 2; i++) {
            int q  = i * 256 + t;
            int r  = q >> 3;
            int c0 = ((q ^ r) & 7) << 3;
            __builtin_amdgcn_global_load_lds(
                (const __attribute__((address_space(1))) void*)(Bb + (size_t)(bn + r) * 1024 + k0 + c0),
                (__attribute__((address_space(3))) void*)(Bs + (i * 256 + w * 64) * 8),
                16, 0, 0);
        }
        __syncthreads();
        #pragma unroll
        for (int kk = 0; kk < 2; kk++) {
            bf16x8 a[4], b[2];
            #pragma unroll
            for (int m = 0; m < 4; m++) {
                int row  = wm + m * 16 + lr;
                int byte = (row * 128 + (kk * 32 + lk) * 2) ^ ((row & 7) << 4);
                a[m] = *reinterpret_cast<const bf16x8*>(reinterpret_cast<const char*>(As) + byte);
            }
            #pragma unroll
            for (int n = 0; n < 2; n++) {
                int row  = wn + n * 16 + lr;
                int byte = (row * 128 + (kk * 32 + lk) * 2) ^ ((row & 7) << 4);
                b[n] = *reinterpret_cast<const bf16x8*>(reinterpret_cast<const char*>(Bs) + byte);
            }
            #pragma unroll
            for (int m = 0; m < 4; m++)
                #pragma unroll
                for (int n = 0; n < 2; n++)
                    acc[m][n] = __builtin_amdgcn_mfma_f32_16x16x32_bf16(a[m], b[n], acc[m][n], 0, 0, 0);
        }
        __syncthreads();
    }

    #pragma unroll
    for (int m = 0; m < 4; m++) {
        #pragma unroll
        for (int j = 0; j < 4; j++) {
            int row = bm + wm + m * 16 + (l >> 4) * 4 + j;
            #pragma unroll
            for (int n = 0; n < 2; n++)
                outb[(size_t)row * D_ + bn + wn + n * 16 + lr] = f2bf(acc[m][n][j]);
        }
    }
}

// depthwise causal conv + SiLU; bf16 in (xi), bf16 out (u). 8 d's per thread.
__global__ void conv_silu(const u16* __restrict__ xib, const float* __restrict__ cw,
                          const float* __restrict__ cb, u16* __restrict__ ub) {
    int i = blockIdx.x * 256 + threadIdx.x;           // octet index over B*L*DI/8
    int e0 = i * 8;
    int d0 = e0 & (DI_ - 1);
    int bl = e0 >> 10;
    int l  = bl & (L_ - 1);
    float acc[8];
    #pragma unroll
    for (int j = 0; j < 8; j++) acc[j] = cb[d0 + j];
    #pragma unroll
    for (int k = 0; k < DC_; k++) {
        int lk = l - (DC_ - 1) + k;
        if (lk >= 0) {
            u16x8 x8 = *reinterpret_cast<const u16x8*>(xib + (size_t)(bl - (DC_ - 1) + k) * DI_ + d0);
            #pragma unroll
            for (int j = 0; j < 8; j++)
                acc[j] = fmaf(bf2f(x8[j]), cw[(d0 + j) * DC_ + k], acc[j]);
        }
    }
    u16x8 r;
    #pragma unroll
    for (int j = 0; j < 8; j++) {
        float v = acc[j] * sigmoidf_(acc[j]);
        r[j] = f2bf(v);
    }
    reinterpret_cast<u16x8*>(ub)[i] = r;
}

// Fused: reduce xproj partials (dt cols into LDS; bx==0 also writes full xdbl)
// then delta = softplus(dts @ W_dt^T + b_dt) -> bf16.
__global__ __launch_bounds__(256) void reduce_dt(
    const float* __restrict__ part, const float* __restrict__ Wdt,
    const float* __restrict__ bdt, float* __restrict__ xdbl,
    u16* __restrict__ deltab) {
    __shared__ float Wl[256 * 33];
    __shared__ float dts[MC_][DR_];
    const int t  = threadIdx.x;
    const int d0 = blockIdx.x * 256;
    const int m0 = blockIdx.y * MC_;

    // Phase A: reduce dt columns for this m-tile
    for (int i = t; i < MC_ * DR_; i += 256) {
        int m = i >> 5, r = i & 31;
        float s = 0.f;
        #pragma unroll
        for (int ks = 0; ks < KS_; ks++) s += part[(size_t)ks * (4096 * 64) + (m0 + m) * 64 + r];
        dts[m][r] = s;
    }
    // bx==0 blocks also emit the full reduced xdbl rows (all 64 cols)
    if (blockIdx.x == 0) {
        for (int i = t; i < MC_ * 64; i += 256) {
            int m = i >> 6, n = i & 63;
            float s = 0.f;
            #pragma unroll
            for (int ks = 0; ks < KS_; ks++) s += part[(size_t)ks * (4096 * 64) + (m0 + m) * 64 + n];
            xdbl[(size_t)(m0 + m) * 64 + n] = s;
        }
    }
    // stage W_dt rows [d0, d0+256) coalesced -> padded LDS
    {
        const float4* src = reinterpret_cast<const float4*>(Wdt + (size_t)d0 * DR_);
        #pragma unroll
        for (int i = 0; i < 8; i++) {
            int e = (i * 256 + t);
            int r4 = e & 7, row = e >> 3;
            float4 v = src[e];
            float* dst = &Wl[row * 33 + r4 * 4];
            dst[0] = v.x; dst[1] = v.y; dst[2] = v.z; dst[3] = v.w;
        }
    }
    __syncthreads();

    float wreg[DR_];
    #pragma unroll
    for (int r = 0; r < DR_; r++) wreg[r] = Wl[t * 33 + r];
    const float bias = bdt[d0 + t];

    for (int m = 0; m < MC_; m++) {
        float a0 = bias, a1 = 0.f, a2 = 0.f, a3 = 0.f;
        #pragma unroll
        for (int r = 0; r < DR_; r += 4) {
            a0 = fmaf(dts[m][r],     wreg[r],     a0);
            a1 = fmaf(dts[m][r + 1], wreg[r + 1], a1);
            a2 = fmaf(dts[m][r + 2], wreg[r + 2], a2);
            a3 = fmaf(dts[m][r + 3], wreg[r + 3], a3);
        }
        float acc = (a0 + a1) + (a2 + a3);
        float sp  = fmaxf(acc, 0.f) + __logf(1.f + __expf(-fabsf(acc)));
        deltab[(size_t)(m0 + m) * DI_ + d0 + t] = f2bf(sp);
    }
}

__global__ void scan_p1(const u16* __restrict__ deltab, const u16* __restrict__ ub,
                        const float* __restrict__ xdbl, const float* __restrict__ A_log,
                        float* __restrict__ hz, float* __restrict__ pA) {
    const int d = blockIdx.x * 256 + threadIdx.x;
    const int c = blockIdx.y;
    const int b = blockIdx.z;
    __shared__ float Brow[CT_][DS_];
    for (int i = threadIdx.x; i < CT_ * DS_; i += 256) {
        int t = i >> 4, s = i & 15;
        Brow[t][s] = xdbl[(size_t)(b * L_ + c * CT_ + t) * NX_ + DR_ + s];
    }
    __syncthreads();
    float a[DS_], h[DS_], p[DS_];
    #pragma unroll
    for (int s = 0; s < DS_; s++) {
        a[s] = -__expf(A_log[d * DS_ + s]);
        h[s] = 0.f; p[s] = 1.f;
    }
    size_t base = (size_t)(b * L_ + c * CT_) * DI_ + d;
    for (int t = 0; t < CT_; t++) {
        float dl = bf2f(deltab[base + (size_t)t * DI_]);
        float uv = bf2f(ub[base + (size_t)t * DI_]);
        float dlu = dl * uv;
        #pragma unroll
        for (int s = 0; s < DS_; s++) {
            float dA = __expf(dl * a[s]);
            p[s] *= dA;
            h[s] = fmaf(dA, h[s], dlu * Brow[t][s]);
        }
    }
    size_t o = ((size_t)(b * NC_ + c) * DI_ + d) * DS_;
    #pragma unroll
    for (int s = 0; s < DS_; s++) { hz[o + s] = h[s]; pA[o + s] = p[s]; }
}

__global__ void carry(const float* __restrict__ hz, const float* __restrict__ pA,
                      float* __restrict__ hin) {
    int idx = blockIdx.x * 256 + threadIdx.x;    // over B*DI*DS
    int b  = idx >> 14;
    int ds = idx & (DI_ * DS_ - 1);
    float h = 0.f;
    for (int c = 0; c < NC_; c++) {
        size_t o = (size_t)(b * NC_ + c) * DI_ * DS_ + ds;
        hin[o] = h;
        h = fmaf(pA[o], h, hz[o]);
    }
}

__global__ void scan_p2(const u16* __restrict__ deltab, const u16* __restrict__ ub,
                        const float* __restrict__ xdbl, const float* __restrict__ A_log,
                        const float* __restrict__ hin, const u16* __restrict__ zb,
                        const float* __restrict__ Dp, u16* __restrict__ yvb) {
    const int d = blockIdx.x * 256 + threadIdx.x;
    const int c = blockIdx.y;
    const int b = blockIdx.z;
    __shared__ float Brow[CT_][DS_];
    __shared__ float Crow[CT_][DS_];
    for (int i = threadIdx.x; i < CT_ * DS_; i += 256) {
        int t = i >> 4, s = i & 15;
        size_t rb = (size_t)(b * L_ + c * CT_ + t) * NX_;
        Brow[t][s] = xdbl[rb + DR_ + s];
        Crow[t][s] = xdbl[rb + DR_ + DS_ + s];
    }
    __syncthreads();
    float a[DS_], h[DS_];
    size_t ho = ((size_t)(b * NC_ + c) * DI_ + d) * DS_;
    #pragma unroll
    for (int s = 0; s < DS_; s++) {
        a[s] = -__expf(A_log[d * DS_ + s]);
        h[s] = hin[ho + s];
    }
    float Dpd = Dp[d];
    size_t base = (size_t)(b * L_ + c * CT_) * DI_ + d;
    for (int t = 0; t < CT_; t++) {
        float dl = bf2f(deltab[base + (size_t)t * DI_]);
        float uv = bf2f(ub[base + (size_t)t * DI_]);
        float dlu = dl * uv;
        float acc = 0.f;
        #pragma unroll
        for (int s = 0; s < DS_; s++) {
            float dA = __expf(dl * a[s]);
            h[s] = fmaf(dA, h[s], dlu * Brow[t][s]);
            acc = fmaf(h[s], Crow[t][s], acc);
        }
        float zv = bf2f(zb[base + (size_t)t * DI_]);
        float yval = fmaf(uv, Dpd, acc);
        yvb[base + (size_t)t * DI_] = f2bf(yval * (zv * sigmoidf_(zv)));
    }
}

__global__ void ln_res(const u16* __restrict__ omb, const float* __restrict__ x,
                       const float* __restrict__ lw, const float* __restrict__ lb,
                       float* __restrict__ out) {
    const int row = blockIdx.x;                    // b*L
    const u16* r = omb + (size_t)row * D_;
    float v0 = bf2f(r[threadIdx.x]), v1 = bf2f(r[threadIdx.x + 256]);
    float s = v0 + v1, sq = v0 * v0 + v1 * v1;
    #pragma unroll
    for (int off = 32; off; off >>= 1) {
        s  += __shfl_down(s, off);
        sq += __shfl_down(sq, off);
    }
    __shared__ float ss[4], ssq[4];
    int w = threadIdx.x >> 6;
    if ((threadIdx.x & 63) == 0) { ss[w] = s; ssq[w] = sq; }
    __syncthreads();
    float ts  = ss[0] + ss[1] + ss[2] + ss[3];
    float tsq = ssq[0] + ssq[1] + ssq[2] + ssq[3];
    float mu  = ts * (1.f / 512.f);
    float var = tsq * (1.f / 512.f) - mu * mu;
    float inv = rsqrtf(var + 1e-6f);
    size_t i0 = (size_t)row * D_ + threadIdx.x;
    out[i0]       = x[i0]       + (v0 - mu) * inv * lw[threadIdx.x]       + lb[threadIdx.x];
    out[i0 + 256] = x[i0 + 256] + (v1 - mu) * inv * lw[threadIdx.x + 256] + lb[threadIdx.x + 256];
}

extern "C" void kernel_launch(void* const* d_in, const int* in_sizes, int n_in,
                              void* d_out, int out_size, void* d_ws, size_t ws_size,
                              hipStream_t stream) {
    const float* x      = (const float*)d_in[0];
    const float* W_in   = (const float*)d_in[1];
    const float* conv_w = (const float*)d_in[2];
    const float* conv_b = (const float*)d_in[3];
    const float* W_xp   = (const float*)d_in[4];
    const float* W_dt   = (const float*)d_in[5];
    const float* b_dt   = (const float*)d_in[6];
    const float* A_log  = (const float*)d_in[7];
    const float* Dp     = (const float*)d_in[8];
    const float* W_out  = (const float*)d_in[9];
    const float* ln_w   = (const float*)d_in[10];
    const float* ln_b   = (const float*)d_in[11];
    float* out = (float*)d_out;

    const size_t NBL = (size_t)B_ * L_ * DI_;          // 4,194,304
    u16* xib  = (u16*)d_ws;                            // B*L*DI bf16
    u16* zb   = xib + NBL;
    u16* ub   = zb  + NBL;
    u16* yvb  = ub  + NBL;
    u16* omb  = yvb + NBL;                             // B*L*D bf16
    u16* xb   = omb + (size_t)B_ * L_ * D_;            // B*L*D bf16
    u16* wb   = xb  + (size_t)B_ * L_ * D_;            // 2*DI*D bf16
    u16* wxb  = wb  + (size_t)2 * DI_ * D_;            // 64*1024 bf16
    u16* wob  = wxb + (size_t)NX_ * DI_;               // D*DI bf16
    u16* deltab = wob + (size_t)D_ * DI_;              // NBL bf16
    float* xdbl  = (float*)(deltab + NBL);             // B*L*NX f32
    float* part  = xdbl + (size_t)B_ * L_ * NX_;       // KS*4096*64 f32
    float* hz    = part + (size_t)KS_ * 4096 * 64;
    float* pAb   = hz + (size_t)B_ * NC_ * DI_ * DS_;
    float* hin   = pAb + (size_t)B_ * NC_ * DI_ * DS_;

    const int n0 = B_ * L_ * D_ / 8, n1 = 2 * DI_ * D_ / 8;
    const int n2 = NX_ * DI_ / 8,    n3 = D_ * DI_ / 8;
    // 0. all fp32 -> bf16 casts in one kernel
    cast_all<<<(n0 + n1 + n2 + n3 + 255) / 256, 256, 0, stream>>>(
        x, xb, n0, W_in, wb, n1, W_xp, wxb, n2, W_out, wob, n3);
    // 1. in_proj (bf16 MFMA): [4096,512] x [2048,512]^T -> xib | zb (bf16)
    gemm_mfma_nt<512, 1024, 1024>
        <<<dim3(2048 / 128, 4096 / 128), 256, 0, stream>>>(xb, wb, xib, zb);
    // 2. depthwise causal conv + SiLU -> ub (bf16)
    conv_silu<<<(int)(NBL / 8 / 256), 256, 0, stream>>>(xib, conv_w, conv_b, ub);
    // 3. x_proj as split-K MFMA
    xproj_mfma<<<dim3(KS_, 4096 / 128), 256, 0, stream>>>(ub, wxb, part);
    // 4. fused reduce + dt_proj + softplus -> xdbl (f32) + deltab (bf16)
    reduce_dt<<<dim3(DI_ / 256, (B_ * L_) / MC_), 256, 0, stream>>>(part, W_dt, b_dt, xdbl, deltab);
    // 5-7. chunked selective scan (3 kernels; launch boundaries are the grid barrier)
    scan_p1<<<dim3(DI_ / 256, NC_, B_), 256, 0, stream>>>(deltab, ub, xdbl, A_log, hz, pAb);
    carry<<<(B_ * DI_ * DS_) / 256, 256, 0, stream>>>(hz, pAb, hin);
    scan_p2<<<dim3(DI_ / 256, NC_, B_), 256, 0, stream>>>(deltab, ub, xdbl, A_log, hin, zb, Dp, yvb);
    // 8. out_proj (bf16 MFMA, 128x64 tile, 256 blocks): -> omb (bf16)
    oproj_mfma<<<dim3(D_ / 64, 4096 / 128), 256, 0, stream>>>(yvb, wob, omb);
    // 9. LayerNorm + residual
    ln_res<<<B_ * L_, 256, 0, stream>>>(omb, x, ln_w, ln_b, out);
}